// Round 12
// baseline (35.999 us; speedup 1.0000x reference)
//
#include <hip/hip_runtime.h>
#include <hip/hip_bf16.h>
#include <math.h>

// out[i,j] = max( (x[i]·W[j]) / (|x_i| |W_j|), 1e-10 ) + b[j]
// B=65536, IN=OUT=256, fp32 in/out.
// Round 12: R11 (1024 thr, 16 waves x 16 rows, full W bf16 LDS, x-first
// register burst, n-outer streamed stores) +
//  (a) sched_barrier(0) pins the 16-load x burst (VGPR=48 showed the compiler
//      serialized it; in-flight was ~1KB/CU vs ~9KB Little's-law need),
//  (b) distributed W staging: wave w stages window w only, computes it
//      pre-barrier (own ds_writes), raw s_barrier (no vmcnt drain), then
//      line-pair-friendly window rotation. Staging leaves the critical path.

using bf16x8 = __attribute__((ext_vector_type(8))) short;   // 8 bf16 = 4 VGPRs
using f32x4  = __attribute__((ext_vector_type(4))) float;

#define W_LDS_BYTES 131072                        // 256 rows * 512 B (bf16, swizzled)
#define LDS_BYTES   (W_LDS_BYTES + 1024 + 1024)   // + winv[256] + b[256]
#define EPS 1e-10f

__device__ __forceinline__ short f2bf(float f) {
    __bf16 h = (__bf16)f;                         // RNE; pairs fuse to v_cvt_pk_bf16_f32
    return __builtin_bit_cast(short, h);
}

__global__ __launch_bounds__(1024, 4) void ffn_cosnorm_kernel(
    const float* __restrict__ x, const float* __restrict__ W,
    const float* __restrict__ b, float* __restrict__ out)
{
    extern __shared__ char smem[];
    float* winv = (float*)(smem + W_LDS_BYTES);           // [256] 1/|W_j|
    float* blds = (float*)(smem + W_LDS_BYTES + 1024);    // [256] bias

    const int t    = threadIdx.x;
    const int lane = t & 63;
    const int wave = t >> 6;                  // 0..15
    const int r16  = lane & 15;               // x row within M-tile (= D col, in-lane)
    const int kg   = lane >> 4;               // 0..3 : K-slice of 8
    const int rxor = (r16 & 7) << 4;          // W-frag read swizzle
    const size_t rowb = (size_t)blockIdx.x * 256 + (size_t)wave * 16;

    const float* xp = x + (rowb + r16) * 256 + kg * 8;

    // ---- x burst FIRST, pinned: all 16 loads in flight before anything else ----
    float4 fa[8], fb[8];                      // 64 VGPR transient
    #pragma unroll
    for (int s = 0; s < 8; ++s) {
        fa[s] = *(const float4*)(xp + s * 32);
        fb[s] = *(const float4*)(xp + s * 32 + 4);
    }
    __builtin_amdgcn_sched_barrier(0);        // burst cannot be sunk/serialized

    // ---- distributed W staging: wave w stages ONLY window w (rows w*16..w*16+15) ----
    {
        const int wrow = wave * 16 + (lane >> 2);   // global W row (output col j)
        const int q    = lane & 3;                  // 64-float quarter of the row
        const float* wr = W + (size_t)wrow * 256 + q * 64;
        const int rx = (wrow & 7) << 4;             // swizzle term
        float ss = 0.f;
        #pragma unroll
        for (int i = 0; i < 8; ++i) {               // 8 groups of 8 floats
            float4 a = *(const float4*)(wr + i * 8);
            float4 c = *(const float4*)(wr + i * 8 + 4);
            ss = fmaf(a.x, a.x, ss); ss = fmaf(a.y, a.y, ss);
            ss = fmaf(a.z, a.z, ss); ss = fmaf(a.w, a.w, ss);
            ss = fmaf(c.x, c.x, ss); ss = fmaf(c.y, c.y, ss);
            ss = fmaf(c.z, c.z, ss); ss = fmaf(c.w, c.w, ss);
            bf16x8 v;
            v[0] = f2bf(a.x); v[1] = f2bf(a.y); v[2] = f2bf(a.z); v[3] = f2bf(a.w);
            v[4] = f2bf(c.x); v[5] = f2bf(c.y); v[6] = f2bf(c.z); v[7] = f2bf(c.w);
            const int off = wrow * 512 + ((q * 128 + i * 16) ^ rx);
            *(bf16x8*)(smem + off) = v;             // ds_write_b128
        }
        ss += __shfl_xor(ss, 1);                    // combine the 4 quarters
        ss += __shfl_xor(ss, 2);
        if (q == 0) winv[wrow] = 1.0f / sqrtf(ss);
        if (q == 1) blds[wrow] = b[wrow];
    }

    // ---- convert x -> bf16 fragments + fp32 sum-of-squares ----
    bf16x8 xb[8];                             // 32 VGPR persistent
    float ssx = 0.f;
    #pragma unroll
    for (int s = 0; s < 8; ++s) {
        float4 a = fa[s], c = fb[s];
        bf16x8 v;
        v[0] = f2bf(a.x); v[1] = f2bf(a.y); v[2] = f2bf(a.z); v[3] = f2bf(a.w);
        v[4] = f2bf(c.x); v[5] = f2bf(c.y); v[6] = f2bf(c.z); v[7] = f2bf(c.w);
        xb[s] = v;
        ssx = fmaf(a.x, a.x, ssx); ssx = fmaf(a.y, a.y, ssx);
        ssx = fmaf(a.z, a.z, ssx); ssx = fmaf(a.w, a.w, ssx);
        ssx = fmaf(c.x, c.x, ssx); ssx = fmaf(c.y, c.y, ssx);
        ssx = fmaf(c.z, c.z, ssx); ssx = fmaf(c.w, c.w, ssx);
    }

    // ---- x_len: butterfly over K-groups; in-lane result ----
    ssx += __shfl_xor(ssx, 16); ssx += __shfl_xor(ssx, 32);
    const float inv = 1.0f / sqrtf(ssx);      // 1/|x_row(r16)|

    const int jb = kg * 4;
    float* op = out + (rowb + r16) * 256;
    const int base = wave & 14;

    auto do_window = [&](int n) {
        f32x4 acc = f32x4{0.f, 0.f, 0.f, 0.f};
        #pragma unroll
        for (int k0 = 0; k0 < 8; ++k0) {
            const int addr = (n * 16 + r16) * 512 + ((k0 * 64 + kg * 16) ^ rxor);
            bf16x8 wfr = *(const bf16x8*)(smem + addr);   // ds_read_b128
            acc = __builtin_amdgcn_mfma_f32_16x16x32_bf16(wfr, xb[k0], acc, 0, 0, 0);
        }
        float4 wv = *(const float4*)(winv + n * 16 + jb);
        float4 bv = *(const float4*)(blds + n * 16 + jb);
        f32x4 o;
        o[0] = fmaxf(acc[0] * (inv * wv.x), EPS) + bv.x;
        o[1] = fmaxf(acc[1] * (inv * wv.y), EPS) + bv.y;
        o[2] = fmaxf(acc[2] * (inv * wv.z), EPS) + bv.z;
        o[3] = fmaxf(acc[3] * (inv * wv.w), EPS) + bv.w;
        *(f32x4*)(op + n * 16 + jb) = o;      // stores stream through compute
    };

    // ---- own window: needs only this wave's ds_writes (compiler lgkmcnt) ----
    do_window(wave);
    __builtin_amdgcn_sched_barrier(0);

    // ---- raw barrier: ds_writes visible, NO vmcnt drain (stores in flight) ----
    asm volatile("s_waitcnt lgkmcnt(0)" ::: "memory");
    __builtin_amdgcn_s_barrier();
    __builtin_amdgcn_sched_barrier(0);

    // ---- remaining 15 windows, line-pair-friendly rotation:
    //      w, w^1, base+2, base+3, base+4, ... (128B out-lines complete on
    //      adjacent iterations for every wave) ----
    #pragma unroll
    for (int i = 1; i < 16; ++i) {
        int n = (base + i) & 15;
        if (i == 1) n = wave ^ 1;
        do_window(n);
        __builtin_amdgcn_sched_barrier(0);    // pin per-n interleave
    }
}

extern "C" void kernel_launch(void* const* d_in, const int* in_sizes, int n_in,
                              void* d_out, int out_size, void* d_ws, size_t ws_size,
                              hipStream_t stream) {
    const float* x = (const float*)d_in[0];
    const float* W = (const float*)d_in[1];
    const float* b = (const float*)d_in[2];
    float* out = (float*)d_out;

    hipFuncSetAttribute((const void*)ffn_cosnorm_kernel,
                        hipFuncAttributeMaxDynamicSharedMemorySize, LDS_BYTES);
    ffn_cosnorm_kernel<<<dim3(256), dim3(1024), LDS_BYTES, stream>>>(x, W, b, out);
}